// Round 7
// baseline (268.246 us; speedup 1.0000x reference)
//
#include <hip/hip_runtime.h>

typedef unsigned short u16;
using bfrag = __attribute__((ext_vector_type(8))) short;   // 8 bf16 (4 VGPRs)
using f32x4 = __attribute__((ext_vector_type(4))) float;   // MFMA C/D

#define PEN  (-10000.0f)
#define RSC  (0.125f)   // 1/sqrt(64)

__device__ __forceinline__ u16 f2bf(float f) {
  union { float f; unsigned u; } v; v.f = f;
  unsigned r = v.u + 0x7fffu + ((v.u >> 16) & 1u);  // RNE
  return (u16)(r >> 16);
}

// async global->LDS DMA, 16 B per lane. LDS dest = wave-uniform base + lane*16.
__device__ __forceinline__ void gload16(const u16* g, u16* l) {
  __builtin_amdgcn_global_load_lds(
      (const __attribute__((address_space(1))) unsigned int*)g,
      (__attribute__((address_space(3))) unsigned int*)l, 16, 0, 0);
}

// ---- prep: tokens fp32->bf16 (blocks 0..8191) + W->WT bf16 (blocks 8192+) --
__global__ __launch_bounds__(256) void prep_k(
    const float* __restrict__ tokens, u16* __restrict__ tok_bf,
    const float* __restrict__ w0, const float* __restrict__ w1,
    const float* __restrict__ w2, const float* __restrict__ w3,
    u16* __restrict__ wt) {
  __shared__ float tile[64][65];
  int id = blockIdx.x, t = threadIdx.x;
  if (id < 8192) {
    int i = id * 256 + t;                        // float4 groups (2097152)
    float4 v = ((const float4*)tokens)[i];
    u16 o[4] = { f2bf(v.x), f2bf(v.y), f2bf(v.z), f2bf(v.w) };
    *(uint2*)(tok_bf + (size_t)i * 4) = *(uint2*)o;
    return;
  }
  int wid = id - 8192;
  int z = wid >> 8, rem = wid & 255;
  const float* W = (z == 0) ? w0 : (z == 1) ? w1 : (z == 2) ? w2 : w3;
  u16* out = wt + (size_t)z * 1024 * 1024;
  int k0 = (rem & 15) * 64, n0 = (rem >> 4) * 64;
#pragma unroll
  for (int i = 0; i < 16; ++i) {
    int idx = i * 256 + t, kk = idx >> 6, nn = idx & 63;
    tile[nn][kk] = W[(size_t)(k0 + kk) * 1024 + n0 + nn];
  }
  __syncthreads();
#pragma unroll
  for (int i = 0; i < 16; ++i) {
    int idx = i * 256 + t, nn = idx >> 6, kk = idx & 63;
    out[(size_t)(n0 + nn) * 1024 + k0 + kk] = f2bf(tile[nn][kk]);
  }
}

// ------ fused QKV GEMM: C[8192][3072] = tok_bf @ WT^T -> Q, K, VT -----------
// Staging and epilogue both live in two [128][64] XOR-swizzled halves: LDS
// is exactly 32 KB -> 5 blocks/CU.
__global__ __launch_bounds__(256) void gemm_qkv_k(
    const u16* __restrict__ A, const u16* __restrict__ WT,
    u16* __restrict__ Q, u16* __restrict__ K, u16* __restrict__ VT) {
  __shared__ alignas(16) u16 smem[16384];          // 32 KB exactly
  u16* As = smem;                                  // [128][64] swizzled
  u16* Bs = smem + 8192;
  int t = threadIdx.x;
  int n0 = blockIdx.x * 128, r0 = blockIdx.y * 128;
  int wave = t >> 6, lane = t & 63, quad = lane >> 4, lcol = lane & 15;
  int wr = wave & 1, wc = wave >> 1;
  int rsel = lane >> 3;                            // row within 8-row DMA group
  int sseg = (lane & 7) ^ rsel;                    // swizzled source segment
  f32x4 acc[4][4];
#pragma unroll
  for (int mt = 0; mt < 4; ++mt)
#pragma unroll
    for (int nt = 0; nt < 4; ++nt) acc[mt][nt] = (f32x4){0.f, 0.f, 0.f, 0.f};

  const u16* a0 = A + (size_t)r0 * 1024 + sseg * 8;
  const u16* b0 = WT + (size_t)n0 * 1024 + sseg * 8;
  int sw = lcol & 7;                               // read-side swizzle key

  for (int kt = 0; kt < 16; ++kt) {
#pragma unroll
    for (int i = 0; i < 4; ++i) {
      int ii = wave * 4 + i;                       // DMA group: rows ii*8..ii*8+7
      int row = ii * 8 + rsel;
      gload16(a0 + (size_t)row * 1024 + kt * 64, As + ii * 512);
      gload16(b0 + (size_t)row * 1024 + kt * 64, Bs + ii * 512);
    }
    __syncthreads();
#pragma unroll
    for (int kh = 0; kh < 2; ++kh) {
      int seg = ((kh * 4 + quad) ^ sw) * 8;
      bfrag af[4], bf[4];
#pragma unroll
      for (int x = 0; x < 4; ++x) {
        af[x] = *(const bfrag*)(As + (wr * 64 + x * 16 + lcol) * 64 + seg);
        bf[x] = *(const bfrag*)(Bs + (wc * 64 + x * 16 + lcol) * 64 + seg);
      }
#pragma unroll
      for (int mt = 0; mt < 4; ++mt)
#pragma unroll
        for (int nt = 0; nt < 4; ++nt)
          acc[mt][nt] = __builtin_amdgcn_mfma_f32_16x16x32_bf16(af[mt], bf[nt], acc[mt][nt], 0, 0, 0);
    }
    __syncthreads();
  }
  // epilogue: C stored into As (cols 0-63) / Bs (cols 64-127), swizzled rows
  {
    int poff = lcol & 7, hb = lcol >> 3, q1_4 = (quad & 1) * 4;
    u16* half = wc ? Bs : As;
#pragma unroll
    for (int mt = 0; mt < 4; ++mt)
#pragma unroll
      for (int nt = 0; nt < 4; ++nt)
#pragma unroll
        for (int r = 0; r < 4; ++r) {
          int row = wr * 64 + mt * 16 + quad * 4 + r;
          int pseg = (nt * 2 + hb) ^ (q1_4 + r);
          half[row * 64 + pseg * 8 + poff] = f2bf(acc[mt][nt][r]);
        }
  }
  __syncthreads();
  int which = n0 >> 10;
  int b = r0 >> 12, s0v = r0 & 4095;
  if (which < 2) {
    int row = t >> 1, seg = t & 1;
    const u16* hsrc = seg ? Bs : As;
    int h = ((n0 & 1023) >> 6) + seg;
    u16* outp = (which == 0 ? Q : K) + (((size_t)(b * 16 + h) * 4096 + s0v + row) << 6);
#pragma unroll
    for (int jj = 0; jj < 8; ++jj)
      *(uint4*)(outp + jj * 8) = *(const uint4*)(hsrc + row * 64 + ((jj ^ (row & 7)) << 3));
  } else {
    int c = t & 127, h = ((n0 & 1023) >> 6) + (c >> 6);
    int c_in = c & 63, cs = c_in >> 3, coff = c & 7;
    const u16* hsrc = (c >> 6) ? Bs : As;
    u16* vtrow = VT + ((size_t)(b * 16 + h) << 18) + ((size_t)(c_in & 63) << 12) + s0v;
    // d = c_in (0..63)
    vtrow = VT + ((size_t)(b * 16 + h) << 18) + ((size_t)c_in << 12) + s0v;
    int sgb = t >> 7;
#pragma unroll
    for (int i = 0; i < 8; ++i) {
      int sg = sgb + 2 * i;
      u16 tmp[8];
#pragma unroll
      for (int rr = 0; rr < 8; ++rr)
        tmp[rr] = hsrc[(sg * 8 + rr) * 64 + ((cs ^ rr) << 3) + coff];
      *(uint4*)(vtrow + sg * 8) = *(uint4*)tmp;
    }
  }
}

// ----------- unified attention: band (x<62) + global split-K (x>=62) --------
// VGPR-staged prefetch pipeline, ping-pong K/VT LDS (unpadded, XOR swizzle),
// wave-private P overlaid on dead Q buffer -> ONE barrier per k-iteration.
__global__ __launch_bounds__(256) void attn_k(
    const u16* __restrict__ Qg, const u16* __restrict__ Kg, const u16* __restrict__ VTg,
    const float* __restrict__ band_mask, const float* __restrict__ from_mask,
    const float* __restrict__ to_mask, u16* __restrict__ ctx,
    float* __restrict__ Opart, float* __restrict__ lbuf) {
  __shared__ alignas(16) u16 QPs[4096];            // Q staging, then P (swizzled)
  __shared__ alignas(16) u16 Ks[2][4096];
  __shared__ alignas(16) u16 VTs[2][4096];

  int t = threadIdx.x;
  int wave = t >> 6, lane = t & 63, quad = lane >> 4, lcol = lane & 15;
  int sw = lcol & 7;
  int bh = blockIdx.y, b = bh >> 4;
  bool is_band = blockIdx.x < 62;
  int j, chunk = 0, nit, sb = 0;
  if (is_band) {
    j = blockIdx.x + 2; nit = 5;
    sb = (j == 2) ? 2 : ((j == 63) ? 61 : j - 1);
  } else {
    int jc = blockIdx.x - 62; j = jc >> 3; chunk = jc & 7; nit = 8;
  }
  bool bandmask_blk = is_band && (j >= 3) && (j <= 62);

  // staging geometry: thread covers (row0 = t>>3, row1 = 32 + t>>3), seg = t&7
  int srow0 = t >> 3, srow1 = 32 + srow0, sseg = t & 7;
  int lds0 = srow0 * 64 + ((sseg ^ (srow0 & 7)) << 3);
  int lds1 = srow1 * 64 + ((sseg ^ (srow1 & 7)) << 3);
  const u16* kbase = Kg + (((size_t)bh * 4096) << 6) + sseg * 8;
  const u16* vbase = VTg + ((size_t)bh << 18) + sseg * 8;

  auto kb_of = [&](int it) {
    return is_band ? ((it < 2) ? it : (sb + it - 2)) : (chunk * 8 + it);
  };

  uint4 kr0, kr1, vr0, vr1;
  auto load_tile = [&](int kb) {
    kr0 = *(const uint4*)(kbase + (((size_t)kb * 64 + srow0) << 6));
    kr1 = *(const uint4*)(kbase + (((size_t)kb * 64 + srow1) << 6));
    vr0 = *(const uint4*)(vbase + ((size_t)srow0 << 12) + kb * 64);
    vr1 = *(const uint4*)(vbase + ((size_t)srow1 << 12) + kb * 64);
  };
  auto write_tile = [&](int buf) {
    *(uint4*)&Ks[buf][lds0] = kr0;  *(uint4*)&Ks[buf][lds1] = kr1;
    *(uint4*)&VTs[buf][lds0] = vr0; *(uint4*)&VTs[buf][lds1] = vr1;
  };

  {  // stage Q + tile 0
    const u16* qsrc = Qg + (((size_t)bh * 4096 + j * 64) << 6) + sseg * 8;
    uint4 q0 = *(const uint4*)(qsrc + srow0 * 64);
    uint4 q1 = *(const uint4*)(qsrc + srow1 * 64);
    *(uint4*)&QPs[lds0] = q0; *(uint4*)&QPs[lds1] = q1;
    load_tile(kb_of(0));
    write_tile(0);
  }

  float l_part[4] = {0.f, 0.f, 0.f, 0.f};
  f32x4 oa[4];
#pragma unroll
  for (int nt = 0; nt < 4; ++nt) oa[nt] = (f32x4){0.f, 0.f, 0.f, 0.f};
  bfrag qf[2];

  int poff = lcol & 7;            // within-seg element offset for P writes
  int hb = lcol >> 3;
  int q1_4 = (quad & 1) * 4;

  for (int it = 0; it < nit; ++it) {
    int buf = it & 1;
    if (it > 0) write_tile(buf);                 // regs staged last iteration
    if (it + 1 < nit) load_tile(kb_of(it + 1));  // prefetch (VGPR, no drain)
    __syncthreads();                             // the ONLY barrier per iter
    if (it == 0) {
#pragma unroll
      for (int kh = 0; kh < 2; ++kh)
        qf[kh] = *(const bfrag*)&QPs[(wave * 16 + lcol) * 64 + (((kh * 4 + quad) ^ sw) << 3)];
    }
    int kb = kb_of(it);

    f32x4 sc[4];
#pragma unroll
    for (int nt = 0; nt < 4; ++nt) sc[nt] = (f32x4){0.f, 0.f, 0.f, 0.f};
#pragma unroll
    for (int kh = 0; kh < 2; ++kh) {
      int seg = ((kh * 4 + quad) ^ sw) << 3;
#pragma unroll
      for (int nt = 0; nt < 4; ++nt) {
        bfrag kf = *(const bfrag*)&Ks[buf][(nt * 16 + lcol) * 64 + seg];
        sc[nt] = __builtin_amdgcn_mfma_f32_16x16x32_bf16(qf[kh], kf, sc[nt], 0, 0, 0);
      }
    }

    // P is wave-private (wave w only touches rows [16w,16w+16)) -> no barrier
    bool use_band = bandmask_blk && (it >= 2);
    if (!use_band) {
#pragma unroll
      for (int nt = 0; nt < 4; ++nt) {
        float tm = to_mask[b * 4096 + kb * 64 + nt * 16 + lcol];
        float pn = (1.0f - tm) * PEN;
#pragma unroll
        for (int r = 0; r < 4; ++r) {
          float p = __expf(sc[nt][r] * RSC + pn);
          l_part[r] += p;
          int pseg = (nt * 2 + hb) ^ (q1_4 + r);
          QPs[(wave * 16 + quad * 4 + r) * 64 + pseg * 8 + poff] = f2bf(p);
        }
      }
    } else {
      const float* bm = band_mask + (((size_t)b * 60 + (j - 3)) << 6) * 192 + (it - 2) * 64;
#pragma unroll
      for (int r = 0; r < 4; ++r) {
        int qrow = wave * 16 + quad * 4 + r;
#pragma unroll
        for (int nt = 0; nt < 4; ++nt) {
          float msk = bm[(size_t)qrow * 192 + nt * 16 + lcol];
          float p = __expf(sc[nt][r] * RSC + (1.0f - msk) * PEN);
          l_part[r] += p;
          int pseg = (nt * 2 + hb) ^ (q1_4 + r);
          QPs[qrow * 64 + pseg * 8 + poff] = f2bf(p);
        }
      }
    }

#pragma unroll
    for (int kh = 0; kh < 2; ++kh) {
      int seg = ((kh * 4 + quad) ^ sw) << 3;
      bfrag pf = *(const bfrag*)&QPs[(wave * 16 + lcol) * 64 + seg];
#pragma unroll
      for (int nt = 0; nt < 4; ++nt) {
        bfrag vf = *(const bfrag*)&VTs[buf][(nt * 16 + lcol) * 64 + seg];
        oa[nt] = __builtin_amdgcn_mfma_f32_16x16x32_bf16(pf, vf, oa[nt], 0, 0, 0);
      }
    }
  }

  if (is_band) {
    float sc_r[4];
#pragma unroll
    for (int r = 0; r < 4; ++r) {
#pragma unroll
      for (int d = 1; d < 16; d <<= 1) l_part[r] += __shfl_xor(l_part[r], d);
      int qrow = wave * 16 + quad * 4 + r;
      sc_r[r] = from_mask[b * 4096 + j * 64 + qrow] / l_part[r];
    }
#pragma unroll
    for (int nt = 0; nt < 4; ++nt)
#pragma unroll
      for (int r = 0; r < 4; ++r) {
        int pseg = (nt * 2 + hb) ^ (q1_4 + r);
        QPs[(wave * 16 + quad * 4 + r) * 64 + pseg * 8 + poff] = f2bf(oa[nt][r] * sc_r[r]);
      }
    __syncthreads();
    u16* dst = ctx + (((size_t)bh * 4096 + j * 64) << 6);
#pragma unroll
    for (int i = 0; i < 2; ++i) {
      int idx = i * 256 + t, row = idx >> 3, s = idx & 7;
      *(uint4*)(dst + row * 64 + s * 8) = *(uint4*)&QPs[row * 64 + ((s ^ (row & 7)) << 3)];
    }
  } else {
    size_t base = (((size_t)(bh * 2 + j) * 8 + chunk) << 6);
#pragma unroll
    for (int nt = 0; nt < 4; ++nt)
#pragma unroll
      for (int r = 0; r < 4; ++r) {
        int row = wave * 16 + quad * 4 + r;
        Opart[((base + row) << 6) + nt * 16 + lcol] = oa[nt][r];
      }
#pragma unroll
    for (int r = 0; r < 4; ++r) {
#pragma unroll
      for (int d = 1; d < 16; d <<= 1) l_part[r] += __shfl_xor(l_part[r], d);
    }
    if (lcol == 0) {
#pragma unroll
      for (int r = 0; r < 4; ++r)
        lbuf[base + wave * 16 + quad * 4 + r] = l_part[r];
    }
  }
}

// ---- combine 8 split-K partials per (bh, j<2) q-block, write ctx bf16 ------
__global__ __launch_bounds__(256) void attn_combine_k(
    const float* __restrict__ Opart, const float* __restrict__ lbuf,
    const float* __restrict__ from_mask, u16* __restrict__ ctx) {
  int blk = blockIdx.x;                 // bh*2 + j
  int bh = blk >> 1, j = blk & 1, b = bh >> 4;
  int t = threadIdx.x;
  int row = t >> 2, dseg = (t & 3) << 4;

  float lt = 0.0f;
  float acc[16];
#pragma unroll
  for (int u = 0; u < 16; ++u) acc[u] = 0.0f;
#pragma unroll
  for (int c = 0; c < 8; ++c) {
    size_t rbase = (((size_t)blk * 8 + c) << 6) + row;
    lt += lbuf[rbase];
    const float* op = Opart + (rbase << 6) + dseg;
#pragma unroll
    for (int u = 0; u < 4; ++u) {
      float4 v = *(const float4*)(op + u * 4);
      acc[u * 4 + 0] += v.x;
      acc[u * 4 + 1] += v.y;
      acc[u * 4 + 2] += v.z;
      acc[u * 4 + 3] += v.w;
    }
  }
  float inv = from_mask[b * 4096 + j * 64 + row] / lt;
  u16* dst = ctx + (((size_t)bh * 4096 + j * 64 + row) << 6) + dseg;
  u16 o[8];
#pragma unroll
  for (int u = 0; u < 8; ++u) o[u] = f2bf(acc[u] * inv);
  *(uint4*)dst = *(uint4*)o;
#pragma unroll
  for (int u = 0; u < 8; ++u) o[u] = f2bf(acc[8 + u] * inv);
  *(uint4*)(dst + 8) = *(uint4*)o;
}

// --- out GEMM: out[8192][1024] fp32 = ctx(b,h,s,d) @ WuT^T + bu, 128x64 tile
__global__ __launch_bounds__(256) void gemm_out_k(
    const u16* __restrict__ ctx, const u16* __restrict__ WTu,
    const float* __restrict__ bu, float* __restrict__ out) {
  __shared__ alignas(16) u16 smem[12288];          // A[128][64] + B[64][64], 24 KB
  u16* As = smem;
  u16* Bs = smem + 8192;
  int t = threadIdx.x;
  int n0 = blockIdx.x * 64, r0 = blockIdx.y * 128;
  int wave = t >> 6, lane = t & 63, quad = lane >> 4, lcol = lane & 15;
  int b = r0 >> 12, s0 = r0 & 4095;
  int rsel = lane >> 3;
  int sseg = (lane & 7) ^ rsel;
  int sw = lcol & 7;
  f32x4 acc[2][4];
#pragma unroll
  for (int mt = 0; mt < 2; ++mt)
#pragma unroll
    for (int nt = 0; nt < 4; ++nt) acc[mt][nt] = (f32x4){0.f, 0.f, 0.f, 0.f};

  const u16* b0 = WTu + (size_t)n0 * 1024 + sseg * 8;
  for (int kt = 0; kt < 16; ++kt) {
    const u16* a0 = ctx + (((size_t)(b * 16 + kt) * 4096 + s0) << 6) + sseg * 8;
#pragma unroll
    for (int i = 0; i < 6; ++i) {
      int ii = wave * 6 + i;                       // 24 DMA groups: 16 A + 8 B
      if (ii < 16) {
        gload16(a0 + (size_t)(ii * 8 + rsel) * 64, As + ii * 512);
      } else {
        int bi = ii - 16;
        gload16(b0 + (size_t)(bi * 8 + rsel) * 1024 + kt * 64, Bs + bi * 512);
      }
    }
    __syncthreads();
#pragma unroll
    for (int kh = 0; kh < 2; ++kh) {
      int seg = ((kh * 4 + quad) ^ sw) * 8;
      bfrag af[2], bf[4];
#pragma unroll
      for (int x = 0; x < 2; ++x)
        af[x] = *(const bfrag*)(As + (wave * 32 + x * 16 + lcol) * 64 + seg);
#pragma unroll
      for (int x = 0; x < 4; ++x)
        bf[x] = *(const bfrag*)(Bs + (x * 16 + lcol) * 64 + seg);
#pragma unroll
      for (int mt = 0; mt < 2; ++mt)
#pragma unroll
        for (int nt = 0; nt < 4; ++nt)
          acc[mt][nt] = __builtin_amdgcn_mfma_f32_16x16x32_bf16(af[mt], bf[nt], acc[mt][nt], 0, 0, 0);
    }
    __syncthreads();
  }
#pragma unroll
  for (int nt = 0; nt < 4; ++nt) {
    int n = n0 + nt * 16 + lcol;
    float bv = bu[n];
#pragma unroll
    for (int mt = 0; mt < 2; ++mt)
#pragma unroll
      for (int r = 0; r < 4; ++r)
        out[(size_t)(r0 + wave * 32 + mt * 16 + quad * 4 + r) * 1024 + n] = acc[mt][nt][r] + bv;
  }
}

extern "C" void kernel_launch(void* const* d_in, const int* in_sizes, int n_in,
                              void* d_out, int out_size, void* d_ws, size_t ws_size,
                              hipStream_t stream) {
  const float* tokens    = (const float*)d_in[0];
  const float* band_mask = (const float*)d_in[1];
  const float* from_mask = (const float*)d_in[2];
  const float* to_mask   = (const float*)d_in[3];
  const float* Wq = (const float*)d_in[4];
  const float* Wk = (const float*)d_in[5];
  const float* Wv = (const float*)d_in[6];
  const float* Wu = (const float*)d_in[7];
  const float* bu = (const float*)d_in[8];
  float* out = (float*)d_out;

  char* ws = (char*)d_ws;
  u16* tok_bf = (u16*)(ws);                                  // 16.8 MB
  u16* WT     = (u16*)(ws + 16777216);                       //  8.4 MB (q,k,v,u)
  u16* Qb     = (u16*)(ws + 16777216 + 8388608);             // 16.8 MB
  u16* Kb     = Qb + 8388608;
  u16* VTb    = Kb + 8388608;
  u16* ctx    = VTb + 8388608;                               // 16.8 MB
  float* Opart = (float*)(ctx + 8388608);                    //  8.4 MB (32*2*8*64*64 f32)
  float* lb    = Opart + (size_t)32 * 2 * 8 * 64 * 64;       //  131 KB

  prep_k<<<9216, 256, 0, stream>>>(tokens, tok_bf, Wq, Wk, Wv, Wu, WT);
  gemm_qkv_k<<<dim3(24, 64), 256, 0, stream>>>(tok_bf, WT, Qb, Kb, VTb);
  attn_k<<<dim3(78, 32), 256, 0, stream>>>(Qb, Kb, VTb, band_mask, from_mask, to_mask,
                                           ctx, Opart, lb);
  attn_combine_k<<<64, 256, 0, stream>>>(Opart, lb, from_mask, ctx);
  gemm_out_k<<<dim3(16, 64), 256, 0, stream>>>(ctx, WT + (size_t)3 * 1024 * 1024, bu, out);
}

// Round 8
// 260.799 us; speedup vs baseline: 1.0286x; 1.0286x over previous
//
#include <hip/hip_runtime.h>

typedef unsigned short u16;
using bfrag = __attribute__((ext_vector_type(8))) short;   // 8 bf16 (4 VGPRs)
using f32x4 = __attribute__((ext_vector_type(4))) float;   // MFMA C/D

#define PEN  (-10000.0f)
#define RSC  (0.125f)   // 1/sqrt(64)

__device__ __forceinline__ u16 f2bf(float f) {
  union { float f; unsigned u; } v; v.f = f;
  unsigned r = v.u + 0x7fffu + ((v.u >> 16) & 1u);  // RNE
  return (u16)(r >> 16);
}

// async global->LDS DMA, 16 B per lane. LDS dest = wave-uniform base + lane*16.
__device__ __forceinline__ void gload16(const u16* g, u16* l) {
  __builtin_amdgcn_global_load_lds(
      (const __attribute__((address_space(1))) unsigned int*)g,
      (__attribute__((address_space(3))) unsigned int*)l, 16, 0, 0);
}

// ---- prep: tokens fp32->bf16 (blocks 0..8191) + W->WT bf16 (blocks 8192+) --
__global__ __launch_bounds__(256) void prep_k(
    const float* __restrict__ tokens, u16* __restrict__ tok_bf,
    const float* __restrict__ w0, const float* __restrict__ w1,
    const float* __restrict__ w2, const float* __restrict__ w3,
    u16* __restrict__ wt) {
  __shared__ float tile[64][65];
  int id = blockIdx.x, t = threadIdx.x;
  if (id < 8192) {
    int i = id * 256 + t;                        // float4 groups (2097152)
    float4 v = ((const float4*)tokens)[i];
    u16 o[4] = { f2bf(v.x), f2bf(v.y), f2bf(v.z), f2bf(v.w) };
    *(uint2*)(tok_bf + (size_t)i * 4) = *(uint2*)o;
    return;
  }
  int wid = id - 8192;
  int z = wid >> 8, rem = wid & 255;
  const float* W = (z == 0) ? w0 : (z == 1) ? w1 : (z == 2) ? w2 : w3;
  u16* out = wt + (size_t)z * 1024 * 1024;
  int k0 = (rem & 15) * 64, n0 = (rem >> 4) * 64;
#pragma unroll
  for (int i = 0; i < 16; ++i) {
    int idx = i * 256 + t, kk = idx >> 6, nn = idx & 63;
    tile[nn][kk] = W[(size_t)(k0 + kk) * 1024 + n0 + nn];
  }
  __syncthreads();
#pragma unroll
  for (int i = 0; i < 16; ++i) {
    int idx = i * 256 + t, nn = idx >> 6, kk = idx & 63;
    out[(size_t)(n0 + nn) * 1024 + k0 + kk] = f2bf(tile[nn][kk]);
  }
}

// ------ fused QKV GEMM: C[8192][3072] = tok_bf @ WT^T -> Q, K, VT -----------
// Launched as two serial r0-half-grids (measurement aid: frees top-5 slots).
__global__ __launch_bounds__(256) void gemm_qkv_k(
    const u16* __restrict__ A, const u16* __restrict__ WT,
    u16* __restrict__ Q, u16* __restrict__ K, u16* __restrict__ VT, int r_off) {
  __shared__ alignas(16) u16 smem[16384];          // 32 KB exactly
  u16* As = smem;                                  // [128][64] swizzled
  u16* Bs = smem + 8192;
  int t = threadIdx.x;
  int n0 = blockIdx.x * 128, r0 = (blockIdx.y + r_off) * 128;
  int wave = t >> 6, lane = t & 63, quad = lane >> 4, lcol = lane & 15;
  int wr = wave & 1, wc = wave >> 1;
  int rsel = lane >> 3;                            // row within 8-row DMA group
  int sseg = (lane & 7) ^ rsel;                    // swizzled source segment
  f32x4 acc[4][4];
#pragma unroll
  for (int mt = 0; mt < 4; ++mt)
#pragma unroll
    for (int nt = 0; nt < 4; ++nt) acc[mt][nt] = (f32x4){0.f, 0.f, 0.f, 0.f};

  const u16* a0 = A + (size_t)r0 * 1024 + sseg * 8;
  const u16* b0 = WT + (size_t)n0 * 1024 + sseg * 8;
  int sw = lcol & 7;                               // read-side swizzle key

  for (int kt = 0; kt < 16; ++kt) {
#pragma unroll
    for (int i = 0; i < 4; ++i) {
      int ii = wave * 4 + i;                       // DMA group: rows ii*8..ii*8+7
      int row = ii * 8 + rsel;
      gload16(a0 + (size_t)row * 1024 + kt * 64, As + ii * 512);
      gload16(b0 + (size_t)row * 1024 + kt * 64, Bs + ii * 512);
    }
    __syncthreads();
#pragma unroll
    for (int kh = 0; kh < 2; ++kh) {
      int seg = ((kh * 4 + quad) ^ sw) * 8;
      bfrag af[4], bf[4];
#pragma unroll
      for (int x = 0; x < 4; ++x) {
        af[x] = *(const bfrag*)(As + (wr * 64 + x * 16 + lcol) * 64 + seg);
        bf[x] = *(const bfrag*)(Bs + (wc * 64 + x * 16 + lcol) * 64 + seg);
      }
#pragma unroll
      for (int mt = 0; mt < 4; ++mt)
#pragma unroll
        for (int nt = 0; nt < 4; ++nt)
          acc[mt][nt] = __builtin_amdgcn_mfma_f32_16x16x32_bf16(af[mt], bf[nt], acc[mt][nt], 0, 0, 0);
    }
    __syncthreads();
  }
  // epilogue: C stored into As (cols 0-63) / Bs (cols 64-127), swizzled rows
  {
    int poff = lcol & 7, hb = lcol >> 3, q1_4 = (quad & 1) * 4;
    u16* half = wc ? Bs : As;
#pragma unroll
    for (int mt = 0; mt < 4; ++mt)
#pragma unroll
      for (int nt = 0; nt < 4; ++nt)
#pragma unroll
        for (int r = 0; r < 4; ++r) {
          int row = wr * 64 + mt * 16 + quad * 4 + r;
          int pseg = (nt * 2 + hb) ^ (q1_4 + r);
          half[row * 64 + pseg * 8 + poff] = f2bf(acc[mt][nt][r]);
        }
  }
  __syncthreads();
  int which = n0 >> 10;
  int b = r0 >> 12, s0v = r0 & 4095;
  if (which < 2) {
    int row = t >> 1, seg = t & 1;
    const u16* hsrc = seg ? Bs : As;
    int h = ((n0 & 1023) >> 6) + seg;
    u16* outp = (which == 0 ? Q : K) + (((size_t)(b * 16 + h) * 4096 + s0v + row) << 6);
#pragma unroll
    for (int jj = 0; jj < 8; ++jj)
      *(uint4*)(outp + jj * 8) = *(const uint4*)(hsrc + row * 64 + ((jj ^ (row & 7)) << 3));
  } else {
    int c = t & 127, h = ((n0 & 1023) >> 6) + (c >> 6);
    int c_in = c & 63, cs = c_in >> 3, coff = c & 7;
    const u16* hsrc = (c >> 6) ? Bs : As;
    u16* vtrow = VT + ((size_t)(b * 16 + h) << 18) + ((size_t)c_in << 12) + s0v;
    int sgb = t >> 7;
#pragma unroll
    for (int i = 0; i < 8; ++i) {
      int sg = sgb + 2 * i;
      u16 tmp[8];
#pragma unroll
      for (int rr = 0; rr < 8; ++rr)
        tmp[rr] = hsrc[(sg * 8 + rr) * 64 + ((cs ^ rr) << 3) + coff];
      *(uint4*)(vtrow + sg * 8) = *(uint4*)tmp;
    }
  }
}

// ----------- unified attention: band (x<62) + global split-K (x>=62) --------
__global__ __launch_bounds__(256) void attn_k(
    const u16* __restrict__ Qg, const u16* __restrict__ Kg, const u16* __restrict__ VTg,
    const float* __restrict__ band_mask, const float* __restrict__ from_mask,
    const float* __restrict__ to_mask, u16* __restrict__ ctx,
    float* __restrict__ Opart, float* __restrict__ lbuf) {
  __shared__ alignas(16) u16 QPs[4096];            // Q staging, then P (swizzled)
  __shared__ alignas(16) u16 Ks[2][4096];
  __shared__ alignas(16) u16 VTs[2][4096];

  int t = threadIdx.x;
  int wave = t >> 6, lane = t & 63, quad = lane >> 4, lcol = lane & 15;
  int sw = lcol & 7;
  int bh = blockIdx.y, b = bh >> 4;
  bool is_band = blockIdx.x < 62;
  int j, chunk = 0, nit, sb = 0;
  if (is_band) {
    j = blockIdx.x + 2; nit = 5;
    sb = (j == 2) ? 2 : ((j == 63) ? 61 : j - 1);
  } else {
    int jc = blockIdx.x - 62; j = jc >> 3; chunk = jc & 7; nit = 8;
  }
  bool bandmask_blk = is_band && (j >= 3) && (j <= 62);

  int srow0 = t >> 3, srow1 = 32 + srow0, sseg = t & 7;
  int lds0 = srow0 * 64 + ((sseg ^ (srow0 & 7)) << 3);
  int lds1 = srow1 * 64 + ((sseg ^ (srow1 & 7)) << 3);
  const u16* kbase = Kg + (((size_t)bh * 4096) << 6) + sseg * 8;
  const u16* vbase = VTg + ((size_t)bh << 18) + sseg * 8;

  auto kb_of = [&](int it) {
    return is_band ? ((it < 2) ? it : (sb + it - 2)) : (chunk * 8 + it);
  };

  uint4 kr0, kr1, vr0, vr1;
  auto load_tile = [&](int kb) {
    kr0 = *(const uint4*)(kbase + (((size_t)kb * 64 + srow0) << 6));
    kr1 = *(const uint4*)(kbase + (((size_t)kb * 64 + srow1) << 6));
    vr0 = *(const uint4*)(vbase + ((size_t)srow0 << 12) + kb * 64);
    vr1 = *(const uint4*)(vbase + ((size_t)srow1 << 12) + kb * 64);
  };
  auto write_tile = [&](int buf) {
    *(uint4*)&Ks[buf][lds0] = kr0;  *(uint4*)&Ks[buf][lds1] = kr1;
    *(uint4*)&VTs[buf][lds0] = vr0; *(uint4*)&VTs[buf][lds1] = vr1;
  };

  {  // stage Q + tile 0
    const u16* qsrc = Qg + (((size_t)bh * 4096 + j * 64) << 6) + sseg * 8;
    uint4 q0 = *(const uint4*)(qsrc + srow0 * 64);
    uint4 q1 = *(const uint4*)(qsrc + srow1 * 64);
    *(uint4*)&QPs[lds0] = q0; *(uint4*)&QPs[lds1] = q1;
    load_tile(kb_of(0));
    write_tile(0);
  }

  float l_part[4] = {0.f, 0.f, 0.f, 0.f};
  f32x4 oa[4];
#pragma unroll
  for (int nt = 0; nt < 4; ++nt) oa[nt] = (f32x4){0.f, 0.f, 0.f, 0.f};
  bfrag qf[2];

  int poff = lcol & 7;            // within-seg element offset for P writes
  int hb = lcol >> 3;
  int q1_4 = (quad & 1) * 4;

  for (int it = 0; it < nit; ++it) {
    int buf = it & 1;
    if (it > 0) write_tile(buf);                 // regs staged last iteration
    if (it + 1 < nit) load_tile(kb_of(it + 1));  // prefetch (VGPR, no drain)
    __syncthreads();                             // the ONLY barrier per iter
    if (it == 0) {
#pragma unroll
      for (int kh = 0; kh < 2; ++kh)
        qf[kh] = *(const bfrag*)&QPs[(wave * 16 + lcol) * 64 + (((kh * 4 + quad) ^ sw) << 3)];
    }
    int kb = kb_of(it);

    f32x4 sc[4];
#pragma unroll
    for (int nt = 0; nt < 4; ++nt) sc[nt] = (f32x4){0.f, 0.f, 0.f, 0.f};
#pragma unroll
    for (int kh = 0; kh < 2; ++kh) {
      int seg = ((kh * 4 + quad) ^ sw) << 3;
#pragma unroll
      for (int nt = 0; nt < 4; ++nt) {
        bfrag kf = *(const bfrag*)&Ks[buf][(nt * 16 + lcol) * 64 + seg];
        sc[nt] = __builtin_amdgcn_mfma_f32_16x16x32_bf16(qf[kh], kf, sc[nt], 0, 0, 0);
      }
    }

    bool use_band = bandmask_blk && (it >= 2);
    if (!use_band) {
#pragma unroll
      for (int nt = 0; nt < 4; ++nt) {
        float tm = to_mask[b * 4096 + kb * 64 + nt * 16 + lcol];
        float pn = (1.0f - tm) * PEN;
#pragma unroll
        for (int r = 0; r < 4; ++r) {
          float p = __expf(sc[nt][r] * RSC + pn);
          l_part[r] += p;
          int pseg = (nt * 2 + hb) ^ (q1_4 + r);
          QPs[(wave * 16 + quad * 4 + r) * 64 + pseg * 8 + poff] = f2bf(p);
        }
      }
    } else {
      const float* bm = band_mask + (((size_t)b * 60 + (j - 3)) << 6) * 192 + (it - 2) * 64;
#pragma unroll
      for (int r = 0; r < 4; ++r) {
        int qrow = wave * 16 + quad * 4 + r;
#pragma unroll
        for (int nt = 0; nt < 4; ++nt) {
          float msk = bm[(size_t)qrow * 192 + nt * 16 + lcol];
          float p = __expf(sc[nt][r] * RSC + (1.0f - msk) * PEN);
          l_part[r] += p;
          int pseg = (nt * 2 + hb) ^ (q1_4 + r);
          QPs[qrow * 64 + pseg * 8 + poff] = f2bf(p);
        }
      }
    }

#pragma unroll
    for (int kh = 0; kh < 2; ++kh) {
      int seg = ((kh * 4 + quad) ^ sw) << 3;
      bfrag pf = *(const bfrag*)&QPs[(wave * 16 + lcol) * 64 + seg];
#pragma unroll
      for (int nt = 0; nt < 4; ++nt) {
        bfrag vf = *(const bfrag*)&VTs[buf][(nt * 16 + lcol) * 64 + seg];
        oa[nt] = __builtin_amdgcn_mfma_f32_16x16x32_bf16(pf, vf, oa[nt], 0, 0, 0);
      }
    }
  }

  if (is_band) {
    float sc_r[4];
#pragma unroll
    for (int r = 0; r < 4; ++r) {
#pragma unroll
      for (int d = 1; d < 16; d <<= 1) l_part[r] += __shfl_xor(l_part[r], d);
      int qrow = wave * 16 + quad * 4 + r;
      sc_r[r] = from_mask[b * 4096 + j * 64 + qrow] / l_part[r];
    }
#pragma unroll
    for (int nt = 0; nt < 4; ++nt)
#pragma unroll
      for (int r = 0; r < 4; ++r) {
        int pseg = (nt * 2 + hb) ^ (q1_4 + r);
        QPs[(wave * 16 + quad * 4 + r) * 64 + pseg * 8 + poff] = f2bf(oa[nt][r] * sc_r[r]);
      }
    __syncthreads();
    u16* dst = ctx + (((size_t)bh * 4096 + j * 64) << 6);
#pragma unroll
    for (int i = 0; i < 2; ++i) {
      int idx = i * 256 + t, row = idx >> 3, s = idx & 7;
      *(uint4*)(dst + row * 64 + s * 8) = *(uint4*)&QPs[row * 64 + ((s ^ (row & 7)) << 3)];
    }
  } else {
    size_t base = (((size_t)(bh * 2 + j) * 8 + chunk) << 6);
#pragma unroll
    for (int nt = 0; nt < 4; ++nt)
#pragma unroll
      for (int r = 0; r < 4; ++r) {
        int row = wave * 16 + quad * 4 + r;
        Opart[((base + row) << 6) + nt * 16 + lcol] = oa[nt][r];
      }
#pragma unroll
    for (int r = 0; r < 4; ++r) {
#pragma unroll
      for (int d = 1; d < 16; d <<= 1) l_part[r] += __shfl_xor(l_part[r], d);
    }
    if (lcol == 0) {
#pragma unroll
      for (int r = 0; r < 4; ++r)
        lbuf[base + wave * 16 + quad * 4 + r] = l_part[r];
    }
  }
}

// ---- combine 8 split-K partials, 256 blocks (16 rows each) -----------------
__global__ __launch_bounds__(256) void attn_combine_k(
    const float* __restrict__ Opart, const float* __restrict__ lbuf,
    const float* __restrict__ from_mask, u16* __restrict__ ctx) {
  int unit = blockIdx.x >> 2, sub = blockIdx.x & 3;   // unit = bh*2+j
  int bh = unit >> 1, j = unit & 1, b = bh >> 4;
  int t = threadIdx.x;
  int row = sub * 16 + (t >> 4);
  int dcol = (t & 15) * 4;
  float lt = 0.0f, a0 = 0.f, a1 = 0.f, a2 = 0.f, a3 = 0.f;
#pragma unroll
  for (int c = 0; c < 8; ++c) {
    size_t rbase = (((size_t)unit * 8 + c) << 6) + row;
    lt += lbuf[rbase];
    float4 v = *(const float4*)(Opart + (rbase << 6) + dcol);
    a0 += v.x; a1 += v.y; a2 += v.z; a3 += v.w;
  }
  float inv = from_mask[b * 4096 + j * 64 + row] / lt;
  u16 o[4] = { f2bf(a0 * inv), f2bf(a1 * inv), f2bf(a2 * inv), f2bf(a3 * inv) };
  *(uint2*)(ctx + (((size_t)bh * 4096 + j * 64 + row) << 6) + dcol) = *(uint2*)o;
}

// ------- out GEMM: out[8192][1024] fp32 = ctx(b,h,s,d) @ WuT^T + bu ---------
__global__ __launch_bounds__(256) void gemm_out_k(
    const u16* __restrict__ ctx, const u16* __restrict__ WTu,
    const float* __restrict__ bu, float* __restrict__ out) {
  __shared__ alignas(16) u16 smem[16384];          // [128][64] x2, swizzled
  u16* As = smem;
  u16* Bs = smem + 8192;
  int t = threadIdx.x;
  int n0 = blockIdx.x * 128, r0 = blockIdx.y * 128;
  int wave = t >> 6, lane = t & 63, quad = lane >> 4, lcol = lane & 15;
  int wr = wave & 1, wc = wave >> 1;
  int b = r0 >> 12, s0 = r0 & 4095;
  int rsel = lane >> 3;
  int sseg = (lane & 7) ^ rsel;
  int sw = lcol & 7;
  f32x4 acc[4][4];
#pragma unroll
  for (int mt = 0; mt < 4; ++mt)
#pragma unroll
    for (int nt = 0; nt < 4; ++nt) acc[mt][nt] = (f32x4){0.f, 0.f, 0.f, 0.f};

  const u16* b0 = WTu + (size_t)n0 * 1024 + sseg * 8;
  for (int kt = 0; kt < 16; ++kt) {
    const u16* a0 = ctx + (((size_t)(b * 16 + kt) * 4096 + s0) << 6) + sseg * 8;
#pragma unroll
    for (int i = 0; i < 4; ++i) {
      int ii = wave * 4 + i;
      int row = ii * 8 + rsel;
      gload16(a0 + (size_t)row * 64, As + ii * 512);
      gload16(b0 + (size_t)row * 1024 + kt * 64, Bs + ii * 512);
    }
    __syncthreads();
#pragma unroll
    for (int kh = 0; kh < 2; ++kh) {
      int seg = ((kh * 4 + quad) ^ sw) * 8;
      bfrag af[4], bf[4];
#pragma unroll
      for (int x = 0; x < 4; ++x) {
        af[x] = *(const bfrag*)(As + (wr * 64 + x * 16 + lcol) * 64 + seg);
        bf[x] = *(const bfrag*)(Bs + (wc * 64 + x * 16 + lcol) * 64 + seg);
      }
#pragma unroll
      for (int mt = 0; mt < 4; ++mt)
#pragma unroll
        for (int nt = 0; nt < 4; ++nt)
          acc[mt][nt] = __builtin_amdgcn_mfma_f32_16x16x32_bf16(af[mt], bf[nt], acc[mt][nt], 0, 0, 0);
    }
    __syncthreads();
  }
#pragma unroll
  for (int nt = 0; nt < 4; ++nt) {
    int n = n0 + wc * 64 + nt * 16 + lcol;
    float bv = bu[n];
#pragma unroll
    for (int mt = 0; mt < 4; ++mt)
#pragma unroll
      for (int r = 0; r < 4; ++r)
        out[(size_t)(r0 + wr * 64 + mt * 16 + quad * 4 + r) * 1024 + n] = acc[mt][nt][r] + bv;
  }
}

extern "C" void kernel_launch(void* const* d_in, const int* in_sizes, int n_in,
                              void* d_out, int out_size, void* d_ws, size_t ws_size,
                              hipStream_t stream) {
  const float* tokens    = (const float*)d_in[0];
  const float* band_mask = (const float*)d_in[1];
  const float* from_mask = (const float*)d_in[2];
  const float* to_mask   = (const float*)d_in[3];
  const float* Wq = (const float*)d_in[4];
  const float* Wk = (const float*)d_in[5];
  const float* Wv = (const float*)d_in[6];
  const float* Wu = (const float*)d_in[7];
  const float* bu = (const float*)d_in[8];
  float* out = (float*)d_out;

  char* ws = (char*)d_ws;
  u16* tok_bf = (u16*)(ws);                                  // 16.8 MB
  u16* WT     = (u16*)(ws + 16777216);                       //  8.4 MB (q,k,v,u)
  u16* Qb     = (u16*)(ws + 16777216 + 8388608);             // 16.8 MB
  u16* Kb     = Qb + 8388608;
  u16* VTb    = Kb + 8388608;
  u16* ctx    = VTb + 8388608;                               // 16.8 MB
  float* Opart = (float*)(ctx + 8388608);                    //  8.4 MB (32*2*8*64*64 f32)
  float* lb    = Opart + (size_t)32 * 2 * 8 * 64 * 64;       //  131 KB

  prep_k<<<9216, 256, 0, stream>>>(tokens, tok_bf, Wq, Wk, Wv, Wu, WT);
  gemm_qkv_k<<<dim3(24, 32), 256, 0, stream>>>(tok_bf, WT, Qb, Kb, VTb, 0);
  gemm_qkv_k<<<dim3(24, 32), 256, 0, stream>>>(tok_bf, WT, Qb, Kb, VTb, 32);
  attn_k<<<dim3(78, 32), 256, 0, stream>>>(Qb, Kb, VTb, band_mask, from_mask, to_mask,
                                           ctx, Opart, lb);
  attn_combine_k<<<256, 256, 0, stream>>>(Opart, lb, from_mask, ctx);
  gemm_out_k<<<dim3(8, 64), 256, 0, stream>>>(ctx, WT + (size_t)3 * 1024 * 1024, bu, out);
}